// Round 10
// baseline (280.926 us; speedup 1.0000x reference)
//
#include <hip/hip_runtime.h>
#include <hip/hip_bf16.h>

#define EPS 1e-6f
#define H 512
#define W 512
#define NB 8
#define NC 8
#define NS 7
#define LOG2E 1.4426950408889634f

typedef float v2f __attribute__((ext_vector_type(2)));

__device__ __forceinline__ int refl(int t, int n) {
    if (t < 0) t = -t;
    if (t >= n) t = 2 * n - 2 - t;
    return t;
}

// ---------------- Kernel A: gaussian-smoothed max only ----------------------------
#define GW 256
#define GR 8
#define NBLK ((W / GW) * (H / GR))   // 128 slots per image

__global__ __launch_bounds__(256) void gauss_max_kernel(
    const float* __restrict__ est, const float* __restrict__ gauss,
    float* __restrict__ blockmax)
{
    const int tx = threadIdx.x, ty = threadIdx.y;
    const int x0 = blockIdx.x * GW;
    const int R  = blockIdx.y * GR + ty * 2;
    const int b  = blockIdx.z;
    const float* e = est + (size_t)b * H * W;
    const int c0 = x0 + tx * 4;

    const float g0 = sqrtf(gauss[0]);
    const float g1 = sqrtf(gauss[6]);
    const float g2 = sqrtf(gauss[12]);

    float4 h0, h1, h2, h3, h4;
    float m = 0.f;

#pragma unroll
    for (int k = 0; k < 6; k++) {
        const float* row = e + refl(R - 2 + k, H) * W;
        float4 v = *(const float4*)&row[c0];
        float em2 = __shfl_up(v.z, 1);
        float em1 = __shfl_up(v.w, 1);
        float ep1 = __shfl_down(v.x, 1);
        float ep2 = __shfl_down(v.y, 1);
        if (tx == 0) {
            if (x0 == 0) { em2 = v.z; em1 = v.y; }
            else         { em2 = row[c0 - 2]; em1 = row[c0 - 1]; }
        }
        if (tx == 63) {
            if (x0 + GW == W) { ep1 = v.z; ep2 = v.y; }
            else              { ep1 = row[c0 + 4]; ep2 = row[c0 + 5]; }
        }
        float4 hc;
        hc.x = g0 * (em2 + v.z) + g1 * (em1 + v.y) + g2 * v.x;
        hc.y = g0 * (em1 + v.w) + g1 * (v.x + v.z) + g2 * v.y;
        hc.z = g0 * (v.x + ep1) + g1 * (v.y + v.w) + g2 * v.z;
        hc.w = g0 * (v.y + ep2) + g1 * (v.z + ep1) + g2 * v.w;
        h0 = h1; h1 = h2; h2 = h3; h3 = h4; h4 = hc;
        if (k >= 4) {
            float ux = g0 * (h0.x + h4.x) + g1 * (h1.x + h3.x) + g2 * h2.x;
            float uy = g0 * (h0.y + h4.y) + g1 * (h1.y + h3.y) + g2 * h2.y;
            float uz = g0 * (h0.z + h4.z) + g1 * (h1.z + h3.z) + g2 * h2.z;
            float uw = g0 * (h0.w + h4.w) + g1 * (h1.w + h3.w) + g2 * h2.w;
            m = fmaxf(m, fmaxf(fmaxf(ux, uy), fmaxf(uz, uw)));
        }
    }

#pragma unroll
    for (int off = 32; off > 0; off >>= 1)
        m = fmaxf(m, __shfl_xor(m, off, 64));
    __shared__ float wm[4];
    if (tx == 0) wm[ty] = m;
    __syncthreads();
    if (tx == 0 && ty == 0) {
        float mm = fmaxf(fmaxf(wm[0], wm[1]), fmaxf(wm[2], wm[3]));
        blockmax[b * NBLK + blockIdx.y * gridDim.x + blockIdx.x] = mm;
    }
}

// ---------------- Kernel B: register-streaming stage, 2 px/lane -------------------
// 1 wave = 128 z-cols (64 lanes x 2), outputs 124 cols (lanes 1..62).
// float2 tap loads (3/row), no LDS, 2 shfls/row, full unroll (shifts -> renames).
#define SLAB 8
#define OUTB 124
#define NBANDS 5     // 5*124 = 620 >= 512

__global__ __launch_bounds__(64) void stage_kernel(
    const float* __restrict__ est, const float* __restrict__ noisy,
    const float* __restrict__ blockmax,
    const float* __restrict__ filt,
    const float* __restrict__ wv, const float* __restrict__ bv,
    const float* __restrict__ lamp, const float* __restrict__ gatep,
    const float* __restrict__ gauss,
    float* __restrict__ out)
{
    const int l = threadIdx.x;
    const int band = blockIdx.x;
    const int R = blockIdx.y * SLAB;
    const int b = blockIdx.z;

    const float* e  = est   + (size_t)b * H * W;
    const float* nz = noisy + (size_t)b * H * W;
    float*       op = out   + (size_t)b * H * W;

    const int c0 = OUTB * band - 2 + 2 * l;       // even; this lane's px cols c0, c0+1
    const int a0 = min(max(c0 - 2, 0), W - 2);
    const int a1 = min(max(c0,     0), W - 2);
    const int a2 = min(max(c0 + 2, 0), W - 2);
    const bool fixL = (c0 == 0);                  // taps -2,-1 -> cols 2,1
    const bool fixR = (c0 == W - 2);              // taps 512,513 -> cols 510,509
    const bool rvin0 = (c0 >= 0) && (c0 < W);
    const bool rvin1 = (c0 + 1 >= 0) && (c0 + 1 < W);
    const bool do_store = (l >= 1) && (l <= 62) && (c0 >= 0) && (c0 <= W - 2);

    // packed filters fp[k][j] = {f[2j][k], f[2j+1][k]}  (uniform)
    v2f fp[9][4], w2p[4], b2p[4];
#pragma unroll
    for (int j = 0; j < 4; j++) {
#pragma unroll
        for (int k = 0; k < 9; k++)
            fp[k][j] = (v2f){filt[(2 * j) * 9 + k], filt[(2 * j + 1) * 9 + k]};
        w2p[j] = (v2f){wv[2 * j] * (2.f * LOG2E), wv[2 * j + 1] * (2.f * LOG2E)};
        b2p[j] = (v2f){bv[2 * j] * (2.f * LOG2E), bv[2 * j + 1] * (2.f * LOG2E)};
    }

    const float g0 = sqrtf(gauss[0]);
    const float g1 = sqrtf(gauss[6]);
    const float g2 = sqrtf(gauss[12]);
    const float lam = lamp[0];
    const float g = __builtin_amdgcn_rcpf(1.f + __builtin_amdgcn_exp2f(-gatep[0] * LOG2E));

    float m = fmaxf(blockmax[b * NBLK + l], blockmax[b * NBLK + 64 + l]);
#pragma unroll
    for (int off = 32; off > 0; off >>= 1)
        m = fmaxf(m, __shfl_xor(m, off, 64));
    const float dinv = __builtin_amdgcn_rcpf(fmaxf(m, EPS));

    auto ld3 = [&](int r, v2f& Lv, v2f& Mv, v2f& Rv) {
        const float* rb = e + (size_t)refl(r, H) * W;
        Lv = *(const v2f*)&rb[a0];
        Mv = *(const v2f*)&rb[a1];
        Rv = *(const v2f*)&rb[a2];
    };
    auto ldn = [&](int r) -> v2f {
        int rr = min(max(r, 0), H - 1);
        return *(const v2f*)&nz[(size_t)rr * W + a1];
    };
    // taps m2..p2 for cols c0-2..c0+3 with image-edge reflect fixups
    auto taps = [&](v2f Lv, v2f Mv, v2f Rv, float& m2, float& m1,
                    float& v0, float& v1, float& p1, float& p2) {
        v0 = Mv.x; v1 = Mv.y;
        m2 = fixL ? Rv.x : Lv.x;
        m1 = fixL ? Mv.y : Lv.y;
        p1 = fixR ? Mv.x : Rv.x;
        p2 = fixR ? Lv.y : Rv.y;
    };
    auto hof = [&](float m2, float m1, float v0, float v1, float p1, float p2) -> v2f {
        return (v2f){ g0 * (m2 + p1) + g1 * (m1 + v1) + g2 * v0,
                      g0 * (m1 + p2) + g1 * (v0 + p1) + g2 * v1 };
    };

    // windows
    v2f h[5];
    float wm1[4], wv0[4], wv1[4], wp1[4];

    // prologue: rows R-3..R
    {
        v2f Lv, Mv, Rv; float m2, m1, v0, v1, p1, p2;
        ld3(R - 3, Lv, Mv, Rv); taps(Lv, Mv, Rv, m2, m1, v0, v1, p1, p2);
        h[1] = hof(m2, m1, v0, v1, p1, p2);
        ld3(R - 2, Lv, Mv, Rv); taps(Lv, Mv, Rv, m2, m1, v0, v1, p1, p2);
        h[2] = hof(m2, m1, v0, v1, p1, p2);
        wm1[1] = m1; wv0[1] = v0; wv1[1] = v1; wp1[1] = p1;
        ld3(R - 1, Lv, Mv, Rv); taps(Lv, Mv, Rv, m2, m1, v0, v1, p1, p2);
        h[3] = hof(m2, m1, v0, v1, p1, p2);
        wm1[2] = m1; wv0[2] = v0; wv1[2] = v1; wp1[2] = p1;
        ld3(R - 0, Lv, Mv, Rv); taps(Lv, Mv, Rv, m2, m1, v0, v1, p1, p2);
        h[4] = hof(m2, m1, v0, v1, p1, p2);
        wm1[3] = m1; wv0[3] = v0; wv1[3] = v1; wp1[3] = p1;
    }
    h[0] = (v2f){0.f, 0.f};
    wm1[0] = 0.f; wv0[0] = 0.f; wv1[0] = 0.f; wp1[0] = 0.f;

    // prefetch queues: est rows R+1..R+3, noisy rows R-2..R
    v2f qL[3], qM[3], qR[3], qn[3];
    ld3(R + 1, qL[0], qM[0], qR[0]);
    ld3(R + 2, qL[1], qM[1], qR[1]);
    ld3(R + 3, qL[2], qM[2], qR[2]);
    qn[0] = ldn(R - 2); qn[1] = ldn(R - 1); qn[2] = ldn(R);

    v2f aU0 = {0,0}, aV0 = {0,0}, aW0 = {0,0};
    v2f aU1 = {0,0}, aV1 = {0,0}, aW1 = {0,0};
    v2f iw_prev = {0,0};

#pragma unroll
    for (int i = 0; i < SLAB + 2; ++i) {
        const int t = R - 1 + i;

        // pop prefetched row t+2; refill row t+5 / noisy t+2
        v2f Lc = qL[0], Mc = qM[0], Rc = qR[0];
        qL[0] = qL[1]; qL[1] = qL[2];
        qM[0] = qM[1]; qM[1] = qM[2];
        qR[0] = qR[1]; qR[1] = qR[2];
        ld3(t + 5, qL[2], qM[2], qR[2]);
        v2f nv = qn[0]; qn[0] = qn[1]; qn[1] = qn[2]; qn[2] = ldn(t + 2);

        float m2, m1, v0, v1, p1, p2;
        taps(Lc, Mc, Rc, m2, m1, v0, v1, p1, p2);
        v2f hn = hof(m2, m1, v0, v1, p1, p2);
        h[0] = h[1]; h[1] = h[2]; h[2] = h[3]; h[3] = h[4]; h[4] = hn;

        v2f iwv = g0 * (h[0] + h[4]) + g1 * (h[1] + h[3]) + g2 * h[2];
        const bool rin = (t >= 0) && (t < H);
        float iwa = (rvin0 && rin) ? fmaxf(iwv.x * dinv, EPS) : 0.f;
        float iwb = (rvin1 && rin) ? fmaxf(iwv.y * dinv, EPS) : 0.f;

        wm1[0] = wm1[1]; wv0[0] = wv0[1]; wv1[0] = wv1[1]; wp1[0] = wp1[1];
        wm1[1] = wm1[2]; wv0[1] = wv0[2]; wv1[1] = wv1[2]; wp1[1] = wp1[2];
        wm1[2] = wm1[3]; wv0[2] = wv0[3]; wv1[2] = wv1[3]; wp1[2] = wp1[3];
        wm1[3] = m1;     wv0[3] = v0;     wv1[3] = v1;     wp1[3] = p1;

        // analysis conv (rows t-1..t+1 in slots 0..2), channel pairs
        v2f ra[4] = {{0,0},{0,0},{0,0},{0,0}};
        v2f rb[4] = {{0,0},{0,0},{0,0},{0,0}};
#pragma unroll
        for (int row = 0; row < 3; row++) {
            const float ta[4] = {wm1[row], wv0[row], wv1[row], wp1[row]};
#pragma unroll
            for (int dx = 0; dx < 3; dx++) {
                const int k = row * 3 + dx;
                v2f ea2 = (v2f){ta[dx], ta[dx]};        // px0 taps m1,v0,v1
                v2f eb2 = (v2f){ta[dx + 1], ta[dx + 1]}; // px1 taps v0,v1,p1
#pragma unroll
                for (int j = 0; j < 4; j++) {
                    ra[j] += fp[k][j] * ea2;
                    rb[j] += fp[k][j] * eb2;
                }
            }
        }
        // activation: z = iw * tanh(w*r+b), tanh in exp2 domain
        v2f zpa[4], zpb[4];
        const v2f iwa2 = (v2f){iwa, iwa}, iwb2 = (v2f){iwb, iwb};
#pragma unroll
        for (int j = 0; j < 4; j++) {
            v2f wra = w2p[j] * ra[j] + b2p[j];
            v2f wrb = w2p[j] * rb[j] + b2p[j];
            v2f tha = (v2f){1.f - 2.f * __builtin_amdgcn_rcpf(__builtin_amdgcn_exp2f(wra.x) + 1.f),
                            1.f - 2.f * __builtin_amdgcn_rcpf(__builtin_amdgcn_exp2f(wra.y) + 1.f)};
            v2f thb = (v2f){1.f - 2.f * __builtin_amdgcn_rcpf(__builtin_amdgcn_exp2f(wrb.x) + 1.f),
                            1.f - 2.f * __builtin_amdgcn_rcpf(__builtin_amdgcn_exp2f(wrb.y) + 1.f)};
            zpa[j] = iwa2 * tha;
            zpb[j] = iwb2 * thb;
        }
        // synthesis partials: s[k] = sum_ch f[ch][k] * z[ch]
        v2f sa[9] = {{0,0},{0,0},{0,0},{0,0},{0,0},{0,0},{0,0},{0,0},{0,0}};
        v2f sb[9] = {{0,0},{0,0},{0,0},{0,0},{0,0},{0,0},{0,0},{0,0},{0,0}};
#pragma unroll
        for (int j = 0; j < 4; j++)
#pragma unroll
            for (int k = 0; k < 9; k++) {
                sa[k] += fp[k][j] * zpa[j];
                sb[k] += fp[k][j] * zpb[j];
            }
        // reduce channel pairs -> per-px scalars, pack px pairs
        v2f U0v = (v2f){sa[0].x + sa[0].y, sb[0].x + sb[0].y};
        v2f V0v = (v2f){sa[1].x + sa[1].y, sb[1].x + sb[1].y};
        v2f W0v = (v2f){sa[2].x + sa[2].y, sb[2].x + sb[2].y};
        v2f U1v = (v2f){sa[3].x + sa[3].y, sb[3].x + sb[3].y};
        v2f V1v = (v2f){sa[4].x + sa[4].y, sb[4].x + sb[4].y};
        v2f W1v = (v2f){sa[5].x + sa[5].y, sb[5].x + sb[5].y};
        v2f U2v = (v2f){sa[6].x + sa[6].y, sb[6].x + sb[6].y};
        v2f V2v = (v2f){sa[7].x + sa[7].y, sb[7].x + sb[7].y};
        v2f W2v = (v2f){sa[8].x + sa[8].y, sb[8].x + sb[8].y};

        v2f dU = aU0 + U2v, dV = aV0 + V2v, dW = aW0 + W2v;
        aU0 = aU1 + U1v; aV0 = aV1 + V1v; aW0 = aW1 + W1v;
        aU1 = U0v;       aV1 = V0v;       aW1 = W0v;

        // diff: col c needs U(c-1) + V(c) + W(c+1); 2 shfls per row total
        float difa = __shfl_up(dU.y, 1) + dV.x + dW.y;
        float difb = dU.x + dV.y + __shfl_down(dW.x, 1);

        if (i >= 2 && do_store) {
            float eoa = wv0[0], eob = wv1[0];   // est row t-1, centers
            float fga = (eoa - nv.x) * __builtin_amdgcn_rcpf(eoa * eoa + EPS);
            float fgb = (eob - nv.y) * __builtin_amdgcn_rcpf(eob * eob + EPS);
            float e2a = eoa - difa - lam * iw_prev.x * fga;
            float e2b = eob - difb - lam * iw_prev.y * fgb;
            float ena = e2a + g * (nv.x - e2a);
            float enb = e2b + g * (nv.y - e2b);
            ena = fminf(fmaxf(ena, EPS), 1.f);
            enb = fminf(fmaxf(enb, EPS), 1.f);
            *(v2f*)&op[(size_t)(t - 1) * W + c0] = (v2f){ena, enb};
        }
        iw_prev = (v2f){iwa, iwb};
    }
}

extern "C" void kernel_launch(void* const* d_in, const int* in_sizes, int n_in,
                              void* d_out, int out_size, void* d_ws, size_t ws_size,
                              hipStream_t stream)
{
    const float* noisy   = (const float*)d_in[0];
    const float* filters = (const float*)d_in[1];  // [7][8][1][3][3]
    const float* wv      = (const float*)d_in[2];  // [7][8]
    const float* bv      = (const float*)d_in[3];  // [7][8]
    const float* lam     = (const float*)d_in[4];  // [7]
    const float* gate    = (const float*)d_in[5];  // [7]
    const float* gauss   = (const float*)d_in[6];  // [25]
    float* out = (float*)d_out;

    char* ws = (char*)d_ws;
    float* ws0      = (float*)ws;                    // 8 MB ping buffer
    float* blockmax = (float*)(ws + (8u << 20));     // 128*8 floats, rewritten each stage

    const float* cur = noisy;
    for (int s = 0; s < NS; s++) {
        float* nxt = (s % 2 == 0) ? out : ws0;  // odd stage count -> final lands in out
        gauss_max_kernel<<<dim3(W / GW, H / GR, NB), dim3(64, 4), 0, stream>>>(
            cur, gauss, blockmax);
        stage_kernel<<<dim3(NBANDS, H / SLAB, NB), dim3(64), 0, stream>>>(
            cur, noisy, blockmax,
            filters + s * NC * 9, wv + s * NC, bv + s * NC, lam + s, gate + s, gauss, nxt);
        cur = nxt;
    }
}